// Round 1
// baseline (1867.356 us; speedup 1.0000x reference)
//
#include <hip/hip_runtime.h>

#define DEVI __device__ __forceinline__

constexpr int Bc = 2, Cc = 64, Tc = 4, Hc = 64, Wc = 64, OFFc = 54, KVc = 27;
constexpr int HW  = Hc * Wc;     // 4096
constexpr int THW = Tc * HW;     // 16384
constexpr int CKV = Cc * KVc;    // 1728

// ---------------- weight transpose: w[o][ck] -> wT[ck][o] ----------------
__global__ __launch_bounds__(256) void transpose_k(const float* __restrict__ w,
                                                   float* __restrict__ wT) {
    int i = blockIdx.x * 256 + threadIdx.x;   // over 64*1728 = 110592
    int o  = i & 63;
    int ck = i >> 6;
    wT[i] = w[o * CKV + ck];
}

// ---------------- offset conv3d: (B,C,T,H,W) -> (B,54,T,H,W) ----------------
__global__ __launch_bounds__(256) void conv_off_kernel(
    const float* __restrict__ x, const float* __restrict__ wgt,
    const float* __restrict__ bias, float* __restrict__ out)
{
    int tid = threadIdx.x;
    int bi  = blockIdx.x;
    int m   = bi & 63;          // 64 blocks per (b,o): THW/256
    int u   = bi >> 6;
    int o   = u % OFFc;
    int b   = u / OFFc;
    int idx = (m << 8) + tid;   // 0..16383
    int w   = idx & 63;
    int h   = (idx >> 6) & 63;
    int t   = idx >> 12;

    float acc = bias[o];
    const float* xb = x + (size_t)b * Cc * THW;
    const float* wo = wgt + (size_t)o * CKV;

    for (int c = 0; c < Cc; ++c) {
        const float* xc = xb + c * THW;
        const float* wc = wo + c * KVc;
        #pragma unroll
        for (int kt = 0; kt < 3; ++kt) {
            int tt = t + kt - 1;
            if ((unsigned)tt < (unsigned)Tc) {
                const float* xt = xc + tt * HW;
                #pragma unroll
                for (int kh = 0; kh < 3; ++kh) {
                    int hh = h + kh - 1;
                    if ((unsigned)hh < (unsigned)Hc) {
                        const float* xr = xt + hh * Wc;
                        #pragma unroll
                        for (int kw = 0; kw < 3; ++kw) {
                            int ww = w + kw - 1;
                            if ((unsigned)ww < (unsigned)Wc)
                                acc = fmaf(xr[ww], wc[kt * 9 + kh * 3 + kw], acc);
                        }
                    }
                }
            }
        }
    }
    out[(((size_t)b * OFFc + o) * Tc + t) * HW + h * Wc + w] = acc;
}

// ---------------- bilinear deform sample ----------------
DEVI float dsample(const float* __restrict__ xb, float dh, float dw,
                   int c, int k, int t, int h, int p)
{
    int kt = k / 9;
    int r  = k - kt * 9;
    int kh = r / 3;
    int kw = r - kh * 3;

    int  ti   = t + kt - 1;
    bool tval = (unsigned)ti < (unsigned)Tc;
    int  tic  = ti < 0 ? 0 : (ti > Tc - 1 ? Tc - 1 : ti);

    float hs = (float)(h + kh - 1) + dh;
    float ws = (float)(p + kw - 1) + dw;
    float fh0 = floorf(hs), fw0 = floorf(ws);
    int   h0 = (int)fh0,   w0 = (int)fw0;
    float lh = hs - fh0,   lw = ws - fw0;
    int   h1 = h0 + 1,     w1 = w0 + 1;

    float m00 = (tval && (unsigned)h0 < 64u && (unsigned)w0 < 64u) ? 1.f : 0.f;
    float m01 = (tval && (unsigned)h0 < 64u && (unsigned)w1 < 64u) ? 1.f : 0.f;
    float m10 = (tval && (unsigned)h1 < 64u && (unsigned)w0 < 64u) ? 1.f : 0.f;
    float m11 = (tval && (unsigned)h1 < 64u && (unsigned)w1 < 64u) ? 1.f : 0.f;

    int hc0 = min(max(h0, 0), 63), hc1 = min(max(h1, 0), 63);
    int wc0 = min(max(w0, 0), 63), wc1 = min(max(w1, 0), 63);

    const float* xct = xb + ((size_t)c * Tc + tic) * HW;
    float v00 = xct[hc0 * 64 + wc0] * m00;
    float v01 = xct[hc0 * 64 + wc1] * m01;
    float v10 = xct[hc1 * 64 + wc0] * m10;
    float v11 = xct[hc1 * 64 + wc1] * m11;

    return (1.f - lh) * ((1.f - lw) * v00 + lw * v01)
         + lh * ((1.f - lw) * v10 + lw * v11);
}

// ---------------- deformable conv as on-the-fly GEMM ----------------
// block = one (b,t,h) row: 64 positions x 64 output channels
template <bool RELU, bool ADDX>
__global__ __launch_bounds__(256) void deform_kernel(
    const float* __restrict__ x, const float* __restrict__ off,
    const float* __restrict__ wT, const float* __restrict__ xres,
    float* __restrict__ out)
{
    __shared__ float s_dh[KVc][64];
    __shared__ float s_dw[KVc][64];
    __shared__ float s_v[8][64];
    __shared__ float s_w[8][64];

    int tid = threadIdx.x;
    int bi  = blockIdx.x;
    int h   = bi & 63;
    int t   = (bi >> 6) & 3;
    int b   = bi >> 8;
    int p   = tid & 63;        // position = w
    int g0  = tid >> 6;        // 0..3
    int ob  = g0 << 4;         // this thread's 16 output channels start

    // stage offsets for this row: dh/dw for all 27 taps x 64 positions
    for (int i = tid; i < KVc * 128; i += 256) {
        int k  = i >> 7;
        int r  = i & 127;
        int j  = r >> 6;
        int ww = r & 63;
        float val = off[(((size_t)b * OFFc + 2 * k + j) * Tc + t) * HW + h * Wc + ww];
        if (j) s_dw[k][ww] = val; else s_dh[k][ww] = val;
    }

    float acc[16];
    #pragma unroll
    for (int j = 0; j < 16; ++j) acc[j] = 0.f;

    const float* xb = x + (size_t)b * Cc * THW;

    int c_a = 0, k_a = g0;        // ck_a = g0, step 8
    int c_b = 0, k_b = g0 + 4;    // ck_b = g0+4, step 8

    for (int ck0 = 0; ck0 < CKV; ck0 += 8) {
        __syncthreads();
        // stage weights for this chunk: wT[(ck0+i)*64 + o]
        ((float*)s_w)[tid]       = wT[(ck0 << 6) + tid];
        ((float*)s_w)[tid + 256] = wT[(ck0 << 6) + 256 + tid];
        // compute 2 bilinear samples per thread into s_v
        s_v[g0][p]     = dsample(xb, s_dh[k_a][p], s_dw[k_a][p], c_a, k_a, t, h, p);
        s_v[g0 + 4][p] = dsample(xb, s_dh[k_b][p], s_dw[k_b][p], c_b, k_b, t, h, p);
        __syncthreads();
        #pragma unroll
        for (int i = 0; i < 8; ++i) {
            float vv = s_v[i][p];
            #pragma unroll
            for (int j = 0; j < 16; ++j)
                acc[j] = fmaf(vv, s_w[i][ob + j], acc[j]);
        }
        k_a += 8; if (k_a >= KVc) { k_a -= KVc; c_a++; }
        k_b += 8; if (k_b >= KVc) { k_b -= KVc; c_b++; }
    }

    size_t obase = (((size_t)b * Cc) * Tc + t) * HW + (size_t)h * Wc + p;
    #pragma unroll
    for (int j = 0; j < 16; ++j) {
        float r = acc[j];
        if (RELU) r = r >= 0.f ? r : 0.1f * r;
        size_t oi = obase + (size_t)(ob + j) * THW;
        if (ADDX) r += xres[oi];
        out[oi] = r;
    }
}

extern "C" void kernel_launch(void* const* d_in, const int* in_sizes, int n_in,
                              void* d_out, int out_size, void* d_ws, size_t ws_size,
                              hipStream_t stream)
{
    const float* x   = (const float*)d_in[0];
    const float* w0  = (const float*)d_in[1];
    const float* ow0 = (const float*)d_in[2];
    const float* ob0 = (const float*)d_in[3];
    const float* w1  = (const float*)d_in[4];
    const float* ow1 = (const float*)d_in[5];
    const float* ob1 = (const float*)d_in[6];
    float* out = (float*)d_out;

    float* y    = (float*)d_ws;                       // 2*64*16384 floats
    float* offb = y    + (size_t)Bc * Cc * THW;       // 2*54*16384 floats
    float* wT0  = offb + (size_t)Bc * OFFc * THW;     // 110592 floats
    float* wT1  = wT0  + (size_t)Cc * CKV;

    transpose_k<<<432, 256, 0, stream>>>(w0, wT0);
    transpose_k<<<432, 256, 0, stream>>>(w1, wT1);

    conv_off_kernel<<<Bc * OFFc * 64, 256, 0, stream>>>(x, ow0, ob0, offb);
    deform_kernel<true, false><<<Bc * Tc * Hc, 256, 0, stream>>>(x, offb, wT0, x, y);
    conv_off_kernel<<<Bc * OFFc * 64, 256, 0, stream>>>(y, ow1, ob1, offb);
    deform_kernel<false, true><<<Bc * Tc * Hc, 256, 0, stream>>>(y, offb, wT1, x, out);
}

// Round 2
// 1607.686 us; speedup vs baseline: 1.1615x; 1.1615x over previous
//
#include <hip/hip_runtime.h>

#define DEVI __device__ __forceinline__

constexpr int Bc = 2, Cc = 64, Tc = 4, Hc = 64, Wc = 64, OFFc = 54, KVc = 27;
constexpr int HW  = Hc * Wc;     // 4096
constexpr int THW = Tc * HW;     // 16384
constexpr int CKV = Cc * KVc;    // 1728

// ---------------- weight transpose: w[o][ck] -> wT[ck][o] (dcn weights) ----------------
__global__ __launch_bounds__(256) void transpose_k(const float* __restrict__ w,
                                                   float* __restrict__ wT) {
    int i = blockIdx.x * 256 + threadIdx.x;   // over 64*1728 = 110592
    int o  = i & 63;
    int ck = i >> 6;
    wT[i] = w[o * CKV + ck];
}

// ------------- offset-weight transpose: ow[o][c][k] -> owT[c][o][k] -------------
__global__ __launch_bounds__(256) void transpose_off_k(const float* __restrict__ w,
                                                       float* __restrict__ wT) {
    int i = blockIdx.x * 256 + threadIdx.x;   // over 54*64*27 = 93312
    if (i >= OFFc * Cc * KVc) return;
    int k = i % KVc;
    int o = (i / KVc) % OFFc;
    int c = i / (KVc * OFFc);
    wT[i] = w[(o * Cc + c) * KVc + k];
}

// ---------------- offset conv3d v2: LDS-tiled, all-taps, 27 outputs/block ----------------
// grid: b(2) x t(4) x htile(32: 2 rows each) x osplit(2) = 512 blocks, 128 threads
__global__ __launch_bounds__(128) void conv_off_v2(
    const float* __restrict__ x, const float* __restrict__ wT,
    const float* __restrict__ bias, float* __restrict__ out)
{
    __shared__ float s_x[12][66];   // [tt*4 + hh][ww+1], zero-padded

    int tid = threadIdx.x;
    int bi  = blockIdx.x;
    int os  = bi & 1;
    int ht  = (bi >> 1) & 31;
    int t   = (bi >> 6) & 3;
    int b   = bi >> 8;
    int h0  = ht * 2;
    int r   = tid >> 6;      // 0..1 output row within tile
    int w   = tid & 63;
    int o0  = os * 27;

    const float* xb = x + (size_t)b * Cc * THW;

    // ---- precompute staging slots (fixed across c) ----
    const float* sp[7];
    bool  sv[7];
    #pragma unroll
    for (int s = 0; s < 7; ++s) {
        int i   = tid + s * 128;
        int row = i / 66;          // 0..11 (+junk for i>=792, masked below)
        int col = i % 66;
        int tt  = t  - 1 + (row >> 2);
        int hh  = h0 - 1 + (row & 3);
        int ww  = col - 1;
        bool v  = (i < 792) && (unsigned)tt < 4u && (unsigned)hh < 64u && (unsigned)ww < 64u;
        sv[s] = v;
        sp[s] = v ? (xb + (size_t)tt * HW + hh * 64 + ww) : xb;
    }

    float acc[27];
    const float* bp = bias + o0;
    #pragma unroll
    for (int o = 0; o < 27; ++o) acc[o] = bp[o];

    // prefetch c = 0
    float ld[7];
    #pragma unroll
    for (int s = 0; s < 7; ++s) ld[s] = sv[s] ? *sp[s] : 0.f;

    float* sx = &s_x[0][0];

    for (int c = 0; c < Cc; ++c) {
        // write staged values (zeros implement padding)
        #pragma unroll
        for (int s = 0; s < 7; ++s)
            if (s < 6 || tid < 792 - 768) sx[tid + s * 128] = ld[s];
        __syncthreads();

        // prefetch next channel (lands during FMA work below)
        if (c + 1 < Cc) {
            #pragma unroll
            for (int s = 0; s < 7; ++s) {
                sp[s] += THW;
                ld[s] = sv[s] ? *sp[s] : 0.f;
            }
        }

        // read 3x3x3 neighborhood for this thread's position
        float v[27];
        #pragma unroll
        for (int kt = 0; kt < 3; ++kt)
            #pragma unroll
            for (int kh = 0; kh < 3; ++kh)
                #pragma unroll
                for (int kw = 0; kw < 3; ++kw)
                    v[kt * 9 + kh * 3 + kw] = s_x[kt * 4 + r + kh][w + kw];

        // block-uniform weights -> s_load; 729 FMAs
        const float* wc = wT + ((size_t)c * OFFc + o0) * KVc;
        #pragma unroll
        for (int o = 0; o < 27; ++o) {
            #pragma unroll
            for (int k = 0; k < 27; ++k)
                acc[o] = fmaf(v[k], wc[o * 27 + k], acc[o]);
        }
        __syncthreads();
    }

    size_t obase = ((size_t)b * OFFc + o0) * THW + t * HW + (size_t)(h0 + r) * 64 + w;
    #pragma unroll
    for (int o = 0; o < 27; ++o)
        out[obase + (size_t)o * THW] = acc[o];
}

// ---------------- bilinear deform sample ----------------
DEVI float dsample(const float* __restrict__ xb, float dh, float dw,
                   int c, int k, int t, int h, int p)
{
    int kt = k / 9;
    int r  = k - kt * 9;
    int kh = r / 3;
    int kw = r - kh * 3;

    int  ti   = t + kt - 1;
    bool tval = (unsigned)ti < (unsigned)Tc;
    int  tic  = ti < 0 ? 0 : (ti > Tc - 1 ? Tc - 1 : ti);

    float hs = (float)(h + kh - 1) + dh;
    float ws = (float)(p + kw - 1) + dw;
    float fh0 = floorf(hs), fw0 = floorf(ws);
    int   h0 = (int)fh0,   w0 = (int)fw0;
    float lh = hs - fh0,   lw = ws - fw0;
    int   h1 = h0 + 1,     w1 = w0 + 1;

    float m00 = (tval && (unsigned)h0 < 64u && (unsigned)w0 < 64u) ? 1.f : 0.f;
    float m01 = (tval && (unsigned)h0 < 64u && (unsigned)w1 < 64u) ? 1.f : 0.f;
    float m10 = (tval && (unsigned)h1 < 64u && (unsigned)w0 < 64u) ? 1.f : 0.f;
    float m11 = (tval && (unsigned)h1 < 64u && (unsigned)w1 < 64u) ? 1.f : 0.f;

    int hc0 = min(max(h0, 0), 63), hc1 = min(max(h1, 0), 63);
    int wc0 = min(max(w0, 0), 63), wc1 = min(max(w1, 0), 63);

    const float* xct = xb + ((size_t)c * Tc + tic) * HW;
    float v00 = xct[hc0 * 64 + wc0] * m00;
    float v01 = xct[hc0 * 64 + wc1] * m01;
    float v10 = xct[hc1 * 64 + wc0] * m10;
    float v11 = xct[hc1 * 64 + wc1] * m11;

    return (1.f - lh) * ((1.f - lw) * v00 + lw * v01)
         + lh * ((1.f - lw) * v10 + lw * v11);
}

// ---------------- deformable conv as on-the-fly GEMM ----------------
// block = one (b,t,h) row: 64 positions x 64 output channels
template <bool RELU, bool ADDX>
__global__ __launch_bounds__(256) void deform_kernel(
    const float* __restrict__ x, const float* __restrict__ off,
    const float* __restrict__ wT, const float* __restrict__ xres,
    float* __restrict__ out)
{
    __shared__ float s_dh[KVc][64];
    __shared__ float s_dw[KVc][64];
    __shared__ float s_v[8][64];
    __shared__ float s_w[8][64];

    int tid = threadIdx.x;
    int bi  = blockIdx.x;
    int h   = bi & 63;
    int t   = (bi >> 6) & 3;
    int b   = bi >> 8;
    int p   = tid & 63;        // position = w
    int g0  = tid >> 6;        // 0..3
    int ob  = g0 << 4;         // this thread's 16 output channels start

    for (int i = tid; i < KVc * 128; i += 256) {
        int k  = i >> 7;
        int r  = i & 127;
        int j  = r >> 6;
        int ww = r & 63;
        float val = off[(((size_t)b * OFFc + 2 * k + j) * Tc + t) * HW + h * Wc + ww];
        if (j) s_dw[k][ww] = val; else s_dh[k][ww] = val;
    }

    float acc[16];
    #pragma unroll
    for (int j = 0; j < 16; ++j) acc[j] = 0.f;

    const float* xb = x + (size_t)b * Cc * THW;

    int c_a = 0, k_a = g0;
    int c_b = 0, k_b = g0 + 4;

    for (int ck0 = 0; ck0 < CKV; ck0 += 8) {
        __syncthreads();
        ((float*)s_w)[tid]       = wT[(ck0 << 6) + tid];
        ((float*)s_w)[tid + 256] = wT[(ck0 << 6) + 256 + tid];
        s_v[g0][p]     = dsample(xb, s_dh[k_a][p], s_dw[k_a][p], c_a, k_a, t, h, p);
        s_v[g0 + 4][p] = dsample(xb, s_dh[k_b][p], s_dw[k_b][p], c_b, k_b, t, h, p);
        __syncthreads();
        #pragma unroll
        for (int i = 0; i < 8; ++i) {
            float vv = s_v[i][p];
            #pragma unroll
            for (int j = 0; j < 16; ++j)
                acc[j] = fmaf(vv, s_w[i][ob + j], acc[j]);
        }
        k_a += 8; if (k_a >= KVc) { k_a -= KVc; c_a++; }
        k_b += 8; if (k_b >= KVc) { k_b -= KVc; c_b++; }
    }

    size_t obase = (((size_t)b * Cc) * Tc + t) * HW + (size_t)h * Wc + p;
    #pragma unroll
    for (int j = 0; j < 16; ++j) {
        float r = acc[j];
        if (RELU) r = r >= 0.f ? r : 0.1f * r;
        size_t oi = obase + (size_t)(ob + j) * THW;
        if (ADDX) r += xres[oi];
        out[oi] = r;
    }
}

extern "C" void kernel_launch(void* const* d_in, const int* in_sizes, int n_in,
                              void* d_out, int out_size, void* d_ws, size_t ws_size,
                              hipStream_t stream)
{
    const float* x   = (const float*)d_in[0];
    const float* w0  = (const float*)d_in[1];
    const float* ow0 = (const float*)d_in[2];
    const float* ob0 = (const float*)d_in[3];
    const float* w1  = (const float*)d_in[4];
    const float* ow1 = (const float*)d_in[5];
    const float* ob1 = (const float*)d_in[6];
    float* out = (float*)d_out;

    float* y    = (float*)d_ws;                       // 2*64*16384
    float* offb = y    + (size_t)Bc * Cc * THW;       // 2*54*16384
    float* wT0  = offb + (size_t)Bc * OFFc * THW;     // 110592
    float* wT1  = wT0  + (size_t)Cc * CKV;            // 110592
    float* owT0 = wT1  + (size_t)Cc * CKV;            // 93312
    float* owT1 = owT0 + (size_t)OFFc * Cc * KVc;     // 93312

    transpose_k<<<432, 256, 0, stream>>>(w0, wT0);
    transpose_k<<<432, 256, 0, stream>>>(w1, wT1);
    transpose_off_k<<<365, 256, 0, stream>>>(ow0, owT0);
    transpose_off_k<<<365, 256, 0, stream>>>(ow1, owT1);

    conv_off_v2<<<512, 128, 0, stream>>>(x, owT0, ob0, offb);
    deform_kernel<true, false><<<Bc * Tc * Hc, 256, 0, stream>>>(x, offb, wT0, x, y);
    conv_off_v2<<<512, 128, 0, stream>>>(y, owT1, ob1, offb);
    deform_kernel<false, true><<<Bc * Tc * Hc, 256, 0, stream>>>(y, offb, wT1, x, out);
}

// Round 4
// 344.415 us; speedup vs baseline: 5.4218x; 4.6679x over previous
//
#include <hip/hip_runtime.h>
#include <hip/hip_bf16.h>

#define DEVI __device__ __forceinline__

constexpr int Bc = 2, Cc = 64, Tc = 4, Hc = 64, Wc = 64, OFFc = 54, KVc = 27;
constexpr int HW  = Hc * Wc;     // 4096
constexpr int THW = Tc * HW;     // 16384
constexpr int CKV = Cc * KVc;    // 1728
constexpr int SRED = 68;         // padded LDS reduce stride (f32)

typedef __attribute__((ext_vector_type(8))) short bf16x8;
typedef __attribute__((ext_vector_type(4))) float f32x4;

DEVI short f2bf(float f) {
    __hip_bfloat16 h = __float2bfloat16(f);
    return *reinterpret_cast<short*>(&h);
}
DEVI float bf2f(short s) {
    unsigned u = ((unsigned)(unsigned short)s) << 16;
    float f; __builtin_memcpy(&f, &u, 4); return f;
}

// ------- weights -> MFMA A layout: wA[o][tap*64 + c], bf16, rows >= ovalid zeroed -------
__global__ __launch_bounds__(256) void w_prep(const float* __restrict__ w,
                                              __hip_bfloat16* __restrict__ wA, int ovalid) {
    int i = blockIdx.x * 256 + threadIdx.x;   // 64*1728 = 110592
    if (i >= 64 * CKV) return;
    int o = i / CKV, r = i - o * CKV;
    int tap = r >> 6, c = r & 63;
    float v = (o < ovalid) ? w[(o * Cc + c) * KVc + tap] : 0.f;
    wA[i] = __float2bfloat16(v);
}

// ------- cast + transpose to channel-last bf16: x[b][c][t][h][w] -> xcl[b][t][h][w][c] -------
__global__ __launch_bounds__(256) void cast_cl(const float* __restrict__ x,
                                               __hip_bfloat16* __restrict__ xcl) {
    __shared__ float s[64][65];
    int tid = threadIdx.x;
    int bi  = blockIdx.x;
    int h = bi & 63, t = (bi >> 6) & 3, b = bi >> 8;

    const float* xp = x + (size_t)b * Cc * THW + t * HW + h * 64;
    int w0 = tid & 63, c0 = tid >> 6;
    #pragma unroll
    for (int i = 0; i < 16; ++i) {
        int c = c0 + i * 4;
        s[c][w0] = xp[(size_t)c * THW + w0];
    }
    __syncthreads();

    __hip_bfloat16* dst = xcl + (size_t)b * (Tc * HW * 64) + (size_t)t * (HW * 64) + (size_t)h * (64 * 64);
    #pragma unroll
    for (int r = 0; r < 2; ++r) {
        int j  = tid + r * 256;
        int w  = j >> 3;
        int c8 = j & 7;
        bf16x8 v;
        #pragma unroll
        for (int jj = 0; jj < 8; ++jj)
            v[jj] = f2bf(s[c8 * 8 + jj][w]);
        *reinterpret_cast<bf16x8*>(dst + w * 64 + c8 * 8) = v;
    }
}

// ---------------- offset conv3d via MFMA, 4 waves split K(taps), LDS reduce ----------------
// block = (b,t,h) row; M=64(54 valid outs) x N=64(w) x K=1728
__global__ __launch_bounds__(256) void conv_off_mfma4(
    const __hip_bfloat16* __restrict__ xcl, const __hip_bfloat16* __restrict__ wA,
    const float* __restrict__ bias, float* __restrict__ offb)
{
    __shared__ float s_red[64 * SRED];
    int tid = threadIdx.x;
    int wv = tid >> 6, lane = tid & 63, l15 = lane & 15, l4 = lane >> 4;
    int bi = blockIdx.x;
    int h = bi & 63, t = (bi >> 6) & 3, b = bi >> 8;

    for (int i = tid; i < 64 * SRED; i += 256) s_red[i] = 0.f;
    __syncthreads();

    f32x4 acc[4][4];
    #pragma unroll
    for (int mf = 0; mf < 4; ++mf)
        #pragma unroll
        for (int nf = 0; nf < 4; ++nf) acc[mf][nf] = (f32x4){0.f, 0.f, 0.f, 0.f};

    const __hip_bfloat16* xb = xcl + ((size_t)b << 20);
    int tap0 = wv * 7, tap1 = min(tap0 + 7, KVc);

    for (int tap = tap0; tap < tap1; ++tap) {
        int kt = tap / 9, rr = tap - kt * 9, kh = rr / 3, kw = rr - kh * 3;
        int tt = t + kt - 1, hh = h + kh - 1;
        bool rowok = (unsigned)tt < 4u && (unsigned)hh < 64u;
        const __hip_bfloat16* brow = xb + (((size_t)(rowok ? tt : 0) * HW + (rowok ? hh : 0) * 64) << 6);
        int wbase = l15 + kw - 1;
        #pragma unroll
        for (int ch = 0; ch < 2; ++ch) {
            int koff = tap * 64 + ch * 32 + l4 * 8;
            bf16x8 af[4];
            #pragma unroll
            for (int mf = 0; mf < 4; ++mf)
                af[mf] = *reinterpret_cast<const bf16x8*>(wA + (mf * 16 + l15) * CKV + koff);
            #pragma unroll
            for (int nf = 0; nf < 4; ++nf) {
                int ws = wbase + nf * 16;
                bf16x8 v = {0, 0, 0, 0, 0, 0, 0, 0};
                if (rowok && (unsigned)ws < 64u)
                    v = *reinterpret_cast<const bf16x8*>(brow + (ws << 6) + ch * 32 + l4 * 8);
                #pragma unroll
                for (int mf = 0; mf < 4; ++mf)
                    acc[mf][nf] = __builtin_amdgcn_mfma_f32_16x16x32_bf16(af[mf], v, acc[mf][nf], 0, 0, 0);
            }
        }
    }

    #pragma unroll
    for (int mf = 0; mf < 4; ++mf)
        #pragma unroll
        for (int nf = 0; nf < 4; ++nf) {
            int n = l15 + nf * 16, o = mf * 16 + l4 * 4;
            float* dst = &s_red[n * SRED + o];
            #pragma unroll
            for (int jj = 0; jj < 4; ++jj) atomicAdd(dst + jj, acc[mf][nf][jj]);
        }
    __syncthreads();

    int o = tid & 63, nb = tid >> 6;
    if (o < OFFc) {
        float bv = bias[o];
        size_t base = ((size_t)(b * OFFc + o) * Tc + t) * HW + h * 64 + nb * 16;
        #pragma unroll
        for (int q = 0; q < 4; ++q) {
            f32x4 v;
            #pragma unroll
            for (int j = 0; j < 4; ++j) v[j] = s_red[(nb * 16 + q * 4 + j) * SRED + o] + bv;
            *reinterpret_cast<f32x4*>(offb + base + q * 4) = v;
        }
    }
}

// ---------------- deformable conv via MFMA implicit GEMM ----------------
// block = (b,t,h) row; samples bilinear from channel-last bf16 src
template <bool L2>
__global__ __launch_bounds__(256) void deform_mfma(
    const __hip_bfloat16* __restrict__ src, const float* __restrict__ offb,
    const __hip_bfloat16* __restrict__ wA,
    const float* __restrict__ xres, float* __restrict__ outf,
    __hip_bfloat16* __restrict__ ycl)
{
    __shared__ float s_off[KVc][2][64];
    __shared__ float s_red[64 * SRED];
    int tid = threadIdx.x;
    int wv = tid >> 6, lane = tid & 63, l15 = lane & 15, l4 = lane >> 4;
    int bi = blockIdx.x;
    int h = bi & 63, t = (bi >> 6) & 3, b = bi >> 8;

    for (int i = tid; i < KVc * 128; i += 256) {
        int k = i >> 7, r = i & 127, j = r >> 6, n = r & 63;
        s_off[k][j][n] = offb[((size_t)(b * OFFc + 2 * k + j) * Tc + t) * HW + h * 64 + n];
    }
    for (int i = tid; i < 64 * SRED; i += 256) s_red[i] = 0.f;
    __syncthreads();

    f32x4 acc[4][4];
    #pragma unroll
    for (int mf = 0; mf < 4; ++mf)
        #pragma unroll
        for (int nf = 0; nf < 4; ++nf) acc[mf][nf] = (f32x4){0.f, 0.f, 0.f, 0.f};

    const __hip_bfloat16* xb = src + ((size_t)b << 20);
    int tap0 = wv * 7, tap1 = min(tap0 + 7, KVc);

    for (int tap = tap0; tap < tap1; ++tap) {
        int kt = tap / 9, rr = tap - kt * 9, kh = rr / 3, kw = rr - kh * 3;
        int tt = t + kt - 1;
        float tm = ((unsigned)tt < 4u) ? 1.f : 0.f;
        int tic = min(max(tt, 0), 3);
        const __hip_bfloat16* xt = xb + ((size_t)tic << 18);
        int ko = tap * 64 + l4 * 8;

        #pragma unroll
        for (int nf = 0; nf < 4; ++nf) {
            int p = l15 + nf * 16;
            float dh = s_off[tap][0][p], dw = s_off[tap][1][p];
            float hs  = (float)(h + kh - 1) + dh;
            float wsf = (float)(p + kw - 1) + dw;
            float fh = floorf(hs), fw = floorf(wsf);
            int h0 = (int)fh, w0 = (int)fw, h1 = h0 + 1, w1 = w0 + 1;
            float lh = hs - fh, lw = wsf - fw;
            float u0 = (1.f - lh) * (((unsigned)h0 < 64u) ? tm : 0.f);
            float u1 = lh         * (((unsigned)h1 < 64u) ? tm : 0.f);
            float q0 = (1.f - lw) * (((unsigned)w0 < 64u) ? 1.f : 0.f);
            float q1 = lw         * (((unsigned)w1 < 64u) ? 1.f : 0.f);
            float c00 = u0 * q0, c01 = u0 * q1, c10 = u1 * q0, c11 = u1 * q1;
            int hc0 = min(max(h0, 0), 63), hc1 = min(max(h1, 0), 63);
            int wc0 = min(max(w0, 0), 63), wc1 = min(max(w1, 0), 63);
            int a00 = (hc0 * 64 + wc0) << 6, a01 = (hc0 * 64 + wc1) << 6;
            int a10 = (hc1 * 64 + wc0) << 6, a11 = (hc1 * 64 + wc1) << 6;

            #pragma unroll
            for (int ch = 0; ch < 2; ++ch) {
                int c0 = ch * 32 + l4 * 8;
                bf16x8 v00 = *reinterpret_cast<const bf16x8*>(xt + a00 + c0);
                bf16x8 v01 = *reinterpret_cast<const bf16x8*>(xt + a01 + c0);
                bf16x8 v10 = *reinterpret_cast<const bf16x8*>(xt + a10 + c0);
                bf16x8 v11 = *reinterpret_cast<const bf16x8*>(xt + a11 + c0);
                bf16x8 bfrag;
                #pragma unroll
                for (int j = 0; j < 8; ++j) {
                    float s = c00 * bf2f(v00[j]) + c01 * bf2f(v01[j])
                            + c10 * bf2f(v10[j]) + c11 * bf2f(v11[j]);
                    bfrag[j] = f2bf(s);
                }
                #pragma unroll
                for (int mf = 0; mf < 4; ++mf) {
                    bf16x8 af = *reinterpret_cast<const bf16x8*>(wA + (mf * 16 + l15) * CKV + ko + ch * 32);
                    acc[mf][nf] = __builtin_amdgcn_mfma_f32_16x16x32_bf16(af, bfrag, acc[mf][nf], 0, 0, 0);
                }
            }
        }
    }

    #pragma unroll
    for (int mf = 0; mf < 4; ++mf)
        #pragma unroll
        for (int nf = 0; nf < 4; ++nf) {
            int n = l15 + nf * 16, o = mf * 16 + l4 * 4;
            float* dst = &s_red[n * SRED + o];
            #pragma unroll
            for (int jj = 0; jj < 4; ++jj) atomicAdd(dst + jj, acc[mf][nf][jj]);
        }
    __syncthreads();

    if (!L2) {
        // leaky-relu + store channel-last bf16 (feeds conv2 + deform2 sampling)
        int n = tid >> 2, og = (tid & 3) << 4;
        __hip_bfloat16* dst = ycl + ((((size_t)(b * Tc + t) * 64 + h) * 64 + n) << 6) + og;
        #pragma unroll
        for (int half = 0; half < 2; ++half) {
            bf16x8 o8;
            #pragma unroll
            for (int j = 0; j < 8; ++j) {
                float v = s_red[n * SRED + og + half * 8 + j];
                v = v >= 0.f ? v : 0.1f * v;
                o8[j] = f2bf(v);
            }
            *reinterpret_cast<bf16x8*>(dst + half * 8) = o8;
        }
    } else {
        // residual add + fp32 channel-first store
        int o = tid & 63, nb = tid >> 6;
        size_t base = ((size_t)(b * Cc + o) * Tc + t) * HW + h * 64 + nb * 16;
        #pragma unroll
        for (int q = 0; q < 4; ++q) {
            f32x4 r, xv = *reinterpret_cast<const f32x4*>(xres + base + q * 4);
            #pragma unroll
            for (int j = 0; j < 4; ++j) r[j] = s_red[(nb * 16 + q * 4 + j) * SRED + o] + xv[j];
            *reinterpret_cast<f32x4*>(outf + base + q * 4) = r;
        }
    }
}

extern "C" void kernel_launch(void* const* d_in, const int* in_sizes, int n_in,
                              void* d_out, int out_size, void* d_ws, size_t ws_size,
                              hipStream_t stream)
{
    const float* x   = (const float*)d_in[0];
    const float* w0  = (const float*)d_in[1];
    const float* ow0 = (const float*)d_in[2];
    const float* ob0 = (const float*)d_in[3];
    const float* w1  = (const float*)d_in[4];
    const float* ow1 = (const float*)d_in[5];
    const float* ob1 = (const float*)d_in[6];
    float* out = (float*)d_out;

    // ws layout — total 16,351,232 bytes (same as round-1 proven footprint)
    float* offb = (float*)d_ws;                                        // 1,769,472 f32
    __hip_bfloat16* xcl  = (__hip_bfloat16*)(offb + (size_t)Bc * OFFc * THW);
    __hip_bfloat16* ycl  = xcl  + (size_t)Bc * THW * 64;               // 2,097,152 bf16
    __hip_bfloat16* owA0 = ycl  + (size_t)Bc * THW * 64;               // 110,592 bf16
    __hip_bfloat16* owA1 = owA0 + (size_t)64 * CKV;
    __hip_bfloat16* wA0  = owA1 + (size_t)64 * CKV;
    __hip_bfloat16* wA1  = wA0  + (size_t)64 * CKV;

    w_prep<<<432, 256, 0, stream>>>(ow0, owA0, OFFc);
    w_prep<<<432, 256, 0, stream>>>(ow1, owA1, OFFc);
    w_prep<<<432, 256, 0, stream>>>(w0,  wA0,  Cc);
    w_prep<<<432, 256, 0, stream>>>(w1,  wA1,  Cc);
    cast_cl<<<512, 256, 0, stream>>>(x, xcl);

    conv_off_mfma4<<<512, 256, 0, stream>>>(xcl, owA0, ob0, offb);
    deform_mfma<false><<<512, 256, 0, stream>>>(xcl, offb, wA0, nullptr, nullptr, ycl);
    conv_off_mfma4<<<512, 256, 0, stream>>>(ycl, owA1, ob1, offb);
    deform_mfma<true><<<512, 256, 0, stream>>>(ycl, offb, wA1, x, out, nullptr);
}

// Round 5
// 270.171 us; speedup vs baseline: 6.9117x; 1.2748x over previous
//
#include <hip/hip_runtime.h>
#include <hip/hip_bf16.h>

#define DEVI __device__ __forceinline__

constexpr int Bc = 2, Cc = 64, Tc = 4, Hc = 64, Wc = 64, OFFc = 54, KVc = 27;
constexpr int HW  = Hc * Wc;     // 4096
constexpr int THW = Tc * HW;     // 16384

typedef __attribute__((ext_vector_type(8))) short bf16x8;
typedef __attribute__((ext_vector_type(4))) float f32x4;

DEVI short f2bf(float f) {
    __hip_bfloat16 h = __float2bfloat16(f);
    return *reinterpret_cast<short*>(&h);
}
DEVI float bf2f(short s) {
    unsigned u = ((unsigned)(unsigned short)s) << 16;
    float f; __builtin_memcpy(&f, &u, 4); return f;
}

// ------- weights -> K-major MFMA A layout -------
// wAk[((tap*2+ch)*4+mf)*512 + l15*32 + q] = w[o=mf*16+l15][c=ch*32+q][tap]
// => per (tap,ch,mf) a wave's A-fragment load is 1KB fully contiguous.
__global__ __launch_bounds__(256) void w_prep(const float* __restrict__ w,
                                              __hip_bfloat16* __restrict__ wAk, int ovalid) {
    int i = blockIdx.x * 256 + threadIdx.x;   // 216*512 = 110592
    if (i >= 216 * 512) return;
    int u = i >> 9, r = i & 511;
    int mf = u & 3, ch = (u >> 2) & 1, tap = u >> 3;
    int o = mf * 16 + (r >> 5), c = ch * 32 + (r & 31);
    float v = (o < ovalid) ? w[(o * Cc + c) * KVc + tap] : 0.f;
    wAk[i] = __float2bfloat16(v);
}

// ------- cast + transpose to channel-last bf16: x[b][c][t][h][w] -> xcl[b][t][h][w][c] -------
__global__ __launch_bounds__(256) void cast_cl(const float* __restrict__ x,
                                               __hip_bfloat16* __restrict__ xcl) {
    __shared__ float s[64][65];
    int tid = threadIdx.x;
    int bi  = blockIdx.x;
    int h = bi & 63, t = (bi >> 6) & 3, b = bi >> 8;

    const float* xp = x + (size_t)b * Cc * THW + t * HW + h * 64;
    int w0 = tid & 63, c0 = tid >> 6;
    #pragma unroll
    for (int i = 0; i < 16; ++i) {
        int c = c0 + i * 4;
        s[c][w0] = xp[(size_t)c * THW + w0];
    }
    __syncthreads();

    __hip_bfloat16* dst = xcl + (((size_t)b * Tc + t) * HW + (size_t)h * 64) * 64;
    #pragma unroll
    for (int r = 0; r < 2; ++r) {
        int j  = tid + r * 256;
        int w  = j >> 3;
        int c8 = j & 7;
        bf16x8 v;
        #pragma unroll
        for (int jj = 0; jj < 8; ++jj)
            v[jj] = f2bf(s[c8 * 8 + jj][w]);
        *reinterpret_cast<bf16x8*>(dst + w * 64 + c8 * 8) = v;
    }
}

// ================= fused offset-conv + deformable-conv =================
// block = (b,t,h,half-row): 32 positions. 4 waves: nf = wv&1 (16-pos group),
// chh = wv>>1 (K channel-half). Phase1: offset conv MFMA -> s_off (LDS).
// Phase2: bilinear-sample implicit GEMM MFMA -> s_red -> fused epilogue.
template <bool L2>
__global__ __launch_bounds__(256, 4) void fused_deform(
    const __hip_bfloat16* __restrict__ src, const __hip_bfloat16* __restrict__ owAk,
    const float* __restrict__ obias, const __hip_bfloat16* __restrict__ wAk,
    const float* __restrict__ xres, float* __restrict__ outf,
    __hip_bfloat16* __restrict__ ycl)
{
    __shared__ float s_off[KVc][2][34];
    __shared__ float s_red[32 * 68];

    int tid = threadIdx.x;
    int wv = tid >> 6, lane = tid & 63, l15 = lane & 15, l4 = lane >> 4;
    int nf = wv & 1, chh = wv >> 1;
    int bi = blockIdx.x;
    int half = bi & 1, h = (bi >> 1) & 63, t = (bi >> 7) & 3, b = bi >> 9;

    int pl = l15 + nf * 16;          // local position 0..31
    int p  = pl + half * 32;         // global w position 0..63
    int cbase = chh * 32 + l4 * 8;   // channel slice of this wave

    // ---- phase 0: init s_off with bias, zero s_red ----
    for (int i = tid; i < KVc * 2 * 34; i += 256) {
        int k = i / 68, rem = i - k * 68, j = rem / 34, pp = rem - j * 34;
        s_off[k][j][pp] = obias[2 * k + j];
    }
    for (int i = tid; i < 32 * 68; i += 256) s_red[i] = 0.f;
    __syncthreads();

    const __hip_bfloat16* xb = src + ((size_t)b << 20);

    // ---- phase 1: offset conv (M=64/54 x N=16 per wave x K=864 per wave) ----
    {
        f32x4 cacc[4];
        #pragma unroll
        for (int mf = 0; mf < 4; ++mf) cacc[mf] = (f32x4){0.f, 0.f, 0.f, 0.f};

        #pragma unroll 3
        for (int tap = 0; tap < KVc; ++tap) {
            int kt = tap / 9, rr = tap - kt * 9, kh = rr / 3, kw = rr - kh * 3;
            int tt = t + kt - 1, hh = h + kh - 1;
            bool rowok = (unsigned)tt < 4u && (unsigned)hh < 64u;
            int ws = p + kw - 1;
            bf16x8 bv = {0, 0, 0, 0, 0, 0, 0, 0};
            if (rowok && (unsigned)ws < 64u)
                bv = *reinterpret_cast<const bf16x8*>(xb + (((size_t)tt * HW + hh * 64 + ws) << 6) + cbase);
            const __hip_bfloat16* ab = owAk + (((tap * 2 + chh) << 11)) + (l15 << 5) + (l4 << 3);
            #pragma unroll
            for (int mf = 0; mf < 4; ++mf) {
                bf16x8 af = *reinterpret_cast<const bf16x8*>(ab + (mf << 9));
                cacc[mf] = __builtin_amdgcn_mfma_f32_16x16x32_bf16(af, bv, cacc[mf], 0, 0, 0);
            }
        }
        #pragma unroll
        for (int mf = 0; mf < 4; ++mf)
            #pragma unroll
            for (int jj = 0; jj < 4; ++jj) {
                int o = mf * 16 + l4 * 4 + jj;
                if (o < OFFc) atomicAdd(&s_off[o >> 1][o & 1][pl], cacc[mf][jj]);
            }
    }
    __syncthreads();

    // ---- phase 2: deformable conv, software-pipelined over taps ----
    f32x4 dacc[4];
    #pragma unroll
    for (int mf = 0; mf < 4; ++mf) dacc[mf] = (f32x4){0.f, 0.f, 0.f, 0.f};

    auto issue = [&](int tap, bf16x8 (&g)[4], float (&cf)[4]) {
        int kt = tap / 9, rr = tap - kt * 9, kh = rr / 3, kw = rr - kh * 3;
        int tt = t + kt - 1;
        float tm = ((unsigned)tt < 4u) ? 1.f : 0.f;
        int tic = min(max(tt, 0), 3);
        const __hip_bfloat16* xt = xb + ((size_t)tic << 18);
        float dh = s_off[tap][0][pl], dw = s_off[tap][1][pl];
        float hs  = (float)(h + kh - 1) + dh;
        float wsf = (float)(p + kw - 1) + dw;
        float fh = floorf(hs), fw = floorf(wsf);
        int h0 = (int)fh, w0 = (int)fw, h1 = h0 + 1, w1 = w0 + 1;
        float lh = hs - fh, lw = wsf - fw;
        float u0 = (1.f - lh) * (((unsigned)h0 < 64u) ? tm : 0.f);
        float u1 = lh         * (((unsigned)h1 < 64u) ? tm : 0.f);
        float q0 = (1.f - lw) * (((unsigned)w0 < 64u) ? 1.f : 0.f);
        float q1 = lw         * (((unsigned)w1 < 64u) ? 1.f : 0.f);
        cf[0] = u0 * q0; cf[1] = u0 * q1; cf[2] = u1 * q0; cf[3] = u1 * q1;
        int hc0 = min(max(h0, 0), 63), hc1 = min(max(h1, 0), 63);
        int wc0 = min(max(w0, 0), 63), wc1 = min(max(w1, 0), 63);
        g[0] = *reinterpret_cast<const bf16x8*>(xt + ((hc0 * 64 + wc0) << 6) + cbase);
        g[1] = *reinterpret_cast<const bf16x8*>(xt + ((hc0 * 64 + wc1) << 6) + cbase);
        g[2] = *reinterpret_cast<const bf16x8*>(xt + ((hc1 * 64 + wc0) << 6) + cbase);
        g[3] = *reinterpret_cast<const bf16x8*>(xt + ((hc1 * 64 + wc1) << 6) + cbase);
    };
    auto consume = [&](int tap, bf16x8 (&g)[4], float (&cf)[4]) {
        bf16x8 bfrag;
        #pragma unroll
        for (int j = 0; j < 8; ++j) {
            float s = cf[0] * bf2f(g[0][j]) + cf[1] * bf2f(g[1][j])
                    + cf[2] * bf2f(g[2][j]) + cf[3] * bf2f(g[3][j]);
            bfrag[j] = f2bf(s);
        }
        const __hip_bfloat16* ab = wAk + (((tap * 2 + chh) << 11)) + (l15 << 5) + (l4 << 3);
        #pragma unroll
        for (int mf = 0; mf < 4; ++mf) {
            bf16x8 af = *reinterpret_cast<const bf16x8*>(ab + (mf << 9));
            dacc[mf] = __builtin_amdgcn_mfma_f32_16x16x32_bf16(af, bfrag, dacc[mf], 0, 0, 0);
        }
    };

    bf16x8 gA[4], gB[4];
    float  cA[4], cB[4];
    issue(0, gA, cA);
    for (int tap = 0; tap + 2 <= KVc; tap += 2) {
        issue(tap + 1, gB, cB);
        consume(tap, gA, cA);
        if (tap + 2 < KVc) issue(tap + 2, gA, cA);
        consume(tap + 1, gB, cB);
    }
    consume(KVc - 1, gA, cA);   // tap 26 (issued in last loop iter)

    #pragma unroll
    for (int mf = 0; mf < 4; ++mf)
        #pragma unroll
        for (int jj = 0; jj < 4; ++jj) {
            int o = mf * 16 + l4 * 4 + jj;
            atomicAdd(&s_red[pl * 68 + o], dacc[mf][jj]);
        }
    __syncthreads();

    // ---- phase 3: fused epilogue ----
    if (!L2) {
        // leaky-relu + channel-last bf16 store (feeds layer-2 conv + sampling)
        int pp = tid >> 3, o8 = (tid & 7) << 3;
        __hip_bfloat16* dst = ycl + ((((size_t)b * Tc + t) * HW + h * 64 + half * 32 + pp) << 6) + o8;
        bf16x8 o8v;
        #pragma unroll
        for (int j = 0; j < 8; ++j) {
            float v = s_red[pp * 68 + o8 + j];
            v = v >= 0.f ? v : 0.1f * v;
            o8v[j] = f2bf(v);
        }
        *reinterpret_cast<bf16x8*>(dst) = o8v;
    } else {
        // residual add + fp32 channel-first store
        int o = tid >> 2, pg = (tid & 3) << 3;
        size_t base = ((size_t)(b * Cc + o) * Tc + t) * HW + h * 64 + half * 32 + pg;
        #pragma unroll
        for (int q = 0; q < 2; ++q) {
            f32x4 r, xv = *reinterpret_cast<const f32x4*>(xres + base + q * 4);
            #pragma unroll
            for (int j = 0; j < 4; ++j) r[j] = s_red[(pg + q * 4 + j) * 68 + o] + xv[j];
            *reinterpret_cast<f32x4*>(outf + base + q * 4) = r;
        }
    }
}

extern "C" void kernel_launch(void* const* d_in, const int* in_sizes, int n_in,
                              void* d_out, int out_size, void* d_ws, size_t ws_size,
                              hipStream_t stream)
{
    const float* x   = (const float*)d_in[0];
    const float* w0  = (const float*)d_in[1];
    const float* ow0 = (const float*)d_in[2];
    const float* ob0 = (const float*)d_in[3];
    const float* w1  = (const float*)d_in[4];
    const float* ow1 = (const float*)d_in[5];
    const float* ob1 = (const float*)d_in[6];
    float* out = (float*)d_out;

    // ws layout (bf16): xcl 2M, ycl 2M, 4 weight buffers 110592 each => ~8.8 MB total
    __hip_bfloat16* xcl  = (__hip_bfloat16*)d_ws;
    __hip_bfloat16* ycl  = xcl  + (size_t)Bc * THW * 64;
    __hip_bfloat16* owA0 = ycl  + (size_t)Bc * THW * 64;
    __hip_bfloat16* owA1 = owA0 + (size_t)216 * 512;
    __hip_bfloat16* wA0  = owA1 + (size_t)216 * 512;
    __hip_bfloat16* wA1  = wA0  + (size_t)216 * 512;

    w_prep<<<432, 256, 0, stream>>>(ow0, owA0, OFFc);
    w_prep<<<432, 256, 0, stream>>>(ow1, owA1, OFFc);
    w_prep<<<432, 256, 0, stream>>>(w0,  wA0,  Cc);
    w_prep<<<432, 256, 0, stream>>>(w1,  wA1,  Cc);
    cast_cl<<<512, 256, 0, stream>>>(x, xcl);

    fused_deform<false><<<1024, 256, 0, stream>>>(xcl, owA0, ob0, wA0, nullptr, nullptr, ycl);
    fused_deform<true><<<1024, 256, 0, stream>>>(ycl, owA1, ob1, wA1, x, out, nullptr);
}